// Round 11
// baseline (2020.545 us; speedup 1.0000x reference)
//
#include <hip/hip_runtime.h>
#include <stdint.h>
#include <stddef.h>

#define VOCAB  128
#define HIDDEN 1024
#define BATCH  64
#define SEQ    512

#define NWG    32     // column slices per group
#define CJ     32     // W_hh columns per WG
#define NVW    4      // vocab rows per WG
#define NTHR   512

#define POISON 0x7F800000u   // impossible for packed (bf16hi(tanh)<<16)|lo

// ws layout in float units
#define E2_OFF   0          // [128][1024] f32
#define WOT_OFF  131072     // [128][1024] bf16
#define BUF_OFF  196608     // [4][64][1024] u32 packed h

typedef __attribute__((ext_vector_type(8))) short short8_t;
typedef __attribute__((ext_vector_type(4))) short short4_t;
typedef __attribute__((ext_vector_type(4))) float f32x4;

// ---------------- coherent (cross-XCD, MALL-level) helpers ----------------
__device__ __forceinline__ uint4 cload4u(const void* p) {
    uint4 v;
    asm volatile("global_load_dwordx4 %0, %1, off sc0 sc1" : "=v"(v) : "v"(p));
    return v;
}
__device__ __forceinline__ void cstoreu(unsigned int* p, unsigned int x) {
    asm volatile("global_store_dword %0, %1, off sc0 sc1" :: "v"(p), "v"(x) : "memory");
}
#define WAITVM0() asm volatile("s_waitcnt vmcnt(0)" ::: "memory")
#define SCHED_FENCE() __builtin_amdgcn_sched_barrier(0)

// ---------------- bf16 helpers ----------------
__device__ __forceinline__ unsigned short bf16_rne(float f) {
    unsigned int u = __float_as_uint(f);
    u += 0x7FFF + ((u >> 16) & 1);
    return (unsigned short)(u >> 16);
}
__device__ __forceinline__ float bf16_f32(unsigned short h) {
    return __uint_as_float(((unsigned int)h) << 16);
}
__device__ __forceinline__ bool ok4(const uint4 v) {
    return v.x != POISON && v.y != POISON && v.z != POISON && v.w != POISON;
}

// ---------------- prep kernels ----------------
__global__ void e2_kernel(const float* __restrict__ emb, const float* __restrict__ W_hx,
                          const float* __restrict__ b_hx, float* __restrict__ E2) {
    int v = blockIdx.x >> 2;
    int j = (blockIdx.x & 3) * 256 + threadIdx.x;
    const float* er = emb + (size_t)v * HIDDEN;
    float acc = 0.f;
#pragma unroll 8
    for (int k = 0; k < HIDDEN; ++k)
        acc += er[k] * W_hx[(size_t)k * HIDDEN + j];
    E2[(size_t)v * HIDDEN + j] = acc + b_hx[j];
}

__global__ void wot_kernel(const float* __restrict__ W_out, unsigned short* __restrict__ WoT) {
    int v  = blockIdx.x;
    int k4 = threadIdx.x;
    ushort4 r;
    r.x = bf16_rne(W_out[(size_t)(k4*4+0)*VOCAB + v]);
    r.y = bf16_rne(W_out[(size_t)(k4*4+1)*VOCAB + v]);
    r.z = bf16_rne(W_out[(size_t)(k4*4+2)*VOCAB + v]);
    r.w = bf16_rne(W_out[(size_t)(k4*4+3)*VOCAB + v]);
    ((ushort4*)(WoT + (size_t)v * HIDDEN))[k4] = r;
}

__global__ void poison_kernel(unsigned int* __restrict__ bufs) {
    int i = blockIdx.x * 256 + threadIdx.x;
    ((uint4*)bufs)[i] = make_uint4(POISON, POISON, POISON, POISON);
}

// ---------------- staging / poll device helpers ----------------
// wave wv stages one h row (1024 elems); lane covers elems i*256 + lane*4, i<4.
__device__ __forceinline__ void issue4(const unsigned int* src, int lane, uint4* d) {
#pragma unroll
    for (int i = 0; i < 4; ++i)
        d[i] = cload4u(src + i * 256 + lane * 4);
}
__device__ __forceinline__ void poll4(const unsigned int* src, int lane, uint4* d) {
    unsigned pend = 0xF;
    int guard = 0;
    for (;;) {
        WAITVM0();
        SCHED_FENCE();   // rule 18: checks AFTER the hardware wait
#pragma unroll
        for (int i = 0; i < 4; ++i)
            if ((pend >> i) & 1u)
                if (ok4(d[i])) pend &= ~(1u << i);
        if (!pend) break;
        if (++guard > (1 << 20)) break;
        __builtin_amdgcn_s_sleep(1);
#pragma unroll
        for (int i = 0; i < 4; ++i)
            if ((pend >> i) & 1u)
                d[i] = cload4u(src + i * 256 + lane * 4);
    }
    SCHED_FENCE();
}
// publish 16 packed elems to swizzled hi/lo LDS rows (row < 8)
__device__ __forceinline__ void publish_u32(short* sHi, short* sLo, int row, int lane,
                                            const uint4* d) {
#pragma unroll
    for (int i = 0; i < 4; ++i) {
        short4_t h4, l4;
        h4[0]=(short)(d[i].x>>16); l4[0]=(short)(d[i].x&0xFFFF);
        h4[1]=(short)(d[i].y>>16); l4[1]=(short)(d[i].y&0xFFFF);
        h4[2]=(short)(d[i].z>>16); l4[2]=(short)(d[i].z&0xFFFF);
        h4[3]=(short)(d[i].w>>16); l4[3]=(short)(d[i].w&0xFFFF);
        int c16 = i * 32 + (lane >> 1);
        int off = row * 1024 + ((c16 ^ row) << 3) + (lane & 1) * 4;
        *(short4_t*)(sHi + off) = h4;
        *(short4_t*)(sLo + off) = l4;
    }
}
__device__ __forceinline__ void publish_f32(short* sHi, short* sLo, int row, int lane,
                                            const float* hr) {
#pragma unroll
    for (int i = 0; i < 4; ++i) {
        float4 f = *(const float4*)(hr + i * 256 + lane * 4);
        float fv[4] = {f.x, f.y, f.z, f.w};
        short4_t h4, l4;
#pragma unroll
        for (int e = 0; e < 4; ++e) {
            unsigned short hi = bf16_rne(fv[e]);
            h4[e] = (short)hi;
            l4[e] = (short)bf16_rne(fv[e] - bf16_f32(hi));
        }
        int c16 = i * 32 + (lane >> 1);
        int off = row * 1024 + ((c16 ^ row) << 3) + (lane & 1) * 4;
        *(short4_t*)(sHi + off) = h4;
        *(short4_t*)(sLo + off) = l4;
    }
}

// ---------------- persistent recurrence kernel ----------------
// grid = 128 WGs (4 pairs x 32 col-slices), 512 threads (8 waves), 114KB LDS.
// Each WG runs TWO independent batch groups (A: rows b0..b0+7, B: b0+8..b0+15)
// phase-shifted so each group's MALL poll hides under the other's compute.
extern "C" __global__ void __launch_bounds__(NTHR)
rnn_kernel(const int* __restrict__ x, const float* __restrict__ h0,
           const float* __restrict__ W_hh,
           const float* __restrict__ E2, const unsigned short* __restrict__ WoT,
           const float* __restrict__ b_out,
           unsigned int* __restrict__ bufs,
           float* __restrict__ logits, float* __restrict__ hf) {
    extern __shared__ char lds[];
    short* sHiA  = (short*)(lds);            // [8][1024] bf16 hi, chunk-swizzled: 16KB
    short* sLoA  = (short*)(lds + 16384);
    short* sHiB  = (short*)(lds + 32768);
    short* sLoB  = (short*)(lds + 49152);
    float* sPartA = (float*)(lds + 65536);   // [8][8][32] f32: 8KB
    float* sPartB = (float*)(lds + 73728);
    float* sPLA   = (float*)(lds + 81920);   // [8][8][4] f32: 1KB
    float* sPLB   = (float*)(lds + 82944);
    int*   sX     = (int*)(lds + 83968);     // [16][512] int: 32KB

    const int bid = blockIdx.x;
    const int w   = bid & 31;
    const int p   = bid >> 5;            // pair id
    const int b0  = p * 16;              // A rows b0.., B rows b0+8..
    const int j0  = w * CJ;
    const int tid  = threadIdx.x;
    const int lane = tid & 63;
    const int wv   = tid >> 6;
    const int r    = lane & 15;
    const int kg   = lane >> 4;

    // ---- prologue: x slice -> LDS ----
    {
        const int4* xs4 = (const int4*)(x + (size_t)b0 * SEQ);
#pragma unroll
        for (int i = 0; i < 4; ++i)
            ((int4*)sX)[tid + 512 * i] = xs4[tid + 512 * i];
    }

    // ---- prologue: W_hh slice -> bf16 hi/lo VGPR fragments ----
    short8_t whi[2][4], wlo[2][4];
    {
#pragma unroll
        for (int ct = 0; ct < 2; ++ct) {
            int col = j0 + ct * 16 + r;
#pragma unroll
            for (int c = 0; c < 4; ++c) {
                int kb = wv * 128 + c * 32 + kg * 8;
#pragma unroll
                for (int e = 0; e < 8; ++e) {
                    float wval = W_hh[(size_t)(kb + e) * HIDDEN + col];
                    unsigned short hi = bf16_rne(wval);
                    whi[ct][c][e] = (short)hi;
                    wlo[ct][c][e] = (short)bf16_rne(wval - bf16_f32(hi));
                }
            }
        }
    }
    // ---- prologue: W_out slice -> bf16 B-frags (cols 4..15 zero) ----
    short8_t wvo[4];
    {
#pragma unroll
        for (int c = 0; c < 4; ++c) {
            int kb = wv * 128 + c * 32 + kg * 8;
#pragma unroll
            for (int e = 0; e < 8; ++e)
                wvo[c][e] = (r < NVW)
                    ? (short)WoT[(size_t)(w * NVW + r) * HIDDEN + kb + e] : (short)0;
        }
    }
    const float bo = b_out[w * NVW + (tid & 3)];
    const int rowA = b0 + wv;           // global batch this wave stages for A
    const int rowB = b0 + 8 + wv;
    __syncthreads();

    uint4 dA[4], dB[4];

#define MFMA_MAIN(SHI, SLO, SPART)                                                   \
    {                                                                                \
        f32x4 acc0 = {0.f,0.f,0.f,0.f}, acc1 = {0.f,0.f,0.f,0.f};                    \
        _Pragma("unroll")                                                            \
        for (int c = 0; c < 4; ++c) {                                                \
            int row = r & 7;                                                         \
            int c8 = wv * 16 + c * 4 + kg;                                           \
            int off = row * 1024 + ((c8 ^ row) << 3);                                \
            short8_t ahi = *(const short8_t*)((SHI) + off);                          \
            short8_t alo = *(const short8_t*)((SLO) + off);                          \
            acc0 = __builtin_amdgcn_mfma_f32_16x16x32_bf16(ahi, whi[0][c], acc0, 0,0,0); \
            acc1 = __builtin_amdgcn_mfma_f32_16x16x32_bf16(ahi, whi[1][c], acc1, 0,0,0); \
            acc0 = __builtin_amdgcn_mfma_f32_16x16x32_bf16(alo, whi[0][c], acc0, 0,0,0); \
            acc1 = __builtin_amdgcn_mfma_f32_16x16x32_bf16(alo, whi[1][c], acc1, 0,0,0); \
            acc0 = __builtin_amdgcn_mfma_f32_16x16x32_bf16(ahi, wlo[0][c], acc0, 0,0,0); \
            acc1 = __builtin_amdgcn_mfma_f32_16x16x32_bf16(ahi, wlo[1][c], acc1, 0,0,0); \
        }                                                                            \
        if (kg < 2) {                                                                \
            _Pragma("unroll")                                                        \
            for (int q = 0; q < 4; ++q) {                                            \
                (SPART)[wv * 256 + (kg * 4 + q) * 32 + r]      = acc0[q];            \
                (SPART)[wv * 256 + (kg * 4 + q) * 32 + 16 + r] = acc1[q];            \
            }                                                                        \
        }                                                                            \
    }

#define MFMA_LOGITS(SHI, SPL)                                                        \
    {                                                                                \
        f32x4 L = {0.f,0.f,0.f,0.f};                                                 \
        _Pragma("unroll")                                                            \
        for (int c = 0; c < 4; ++c) {                                                \
            int row = r & 7;                                                         \
            int c8 = wv * 16 + c * 4 + kg;                                           \
            short8_t a8 = *(const short8_t*)((SHI) + row * 1024 + ((c8 ^ row) << 3)); \
            L = __builtin_amdgcn_mfma_f32_16x16x32_bf16(a8, wvo[c], L, 0,0,0);       \
        }                                                                            \
        if (kg < 2 && r < NVW) {                                                     \
            _Pragma("unroll")                                                        \
            for (int q = 0; q < 4; ++q)                                              \
                (SPL)[wv * 32 + (kg * 4 + q) * 4 + r] = L[q];                        \
        }                                                                            \
    }

#define FINISH(SPART, E2P, GB)                                                       \
    if (tid < 256) {                                                                 \
        float s = 0.f;                                                               \
        _Pragma("unroll")                                                            \
        for (int z = 0; z < 8; ++z) s += (SPART)[z * 256 + tid];                     \
        float hn = tanhf(s + (E2P));                                                 \
        unsigned short hi = bf16_rne(hn);                                            \
        unsigned short lo = bf16_rne(hn - bf16_f32(hi));                             \
        unsigned int pk = ((unsigned int)hi << 16) | (unsigned int)lo;               \
        size_t idx = ((size_t)((GB) + (tid >> 5)) << 10) + j0 + (tid & 31);          \
        cstoreu(bufs + ((size_t)(t & 3) << 16) + idx, pk);                           \
        cstoreu(bufs + ((size_t)((t + 2) & 3) << 16) + idx, POISON);                 \
        if (t == SEQ - 1) hf[idx] = hn;                                              \
    }

#define LREDUCE(SPL, GB, TP)                                                         \
    if (tid < 32) {                                                                  \
        int b = tid >> 2, v = tid & 3;                                               \
        float s = 0.f;                                                               \
        _Pragma("unroll")                                                            \
        for (int z = 0; z < 8; ++z) s += (SPL)[z * 32 + b * 4 + v];                  \
        logits[((size_t)((GB) + b) * SEQ + (TP)) * VOCAB + w * NVW + v] = s + bo;    \
    }

    for (int t = 0; t < SEQ; ++t) {
        // ================= A phase =================
        if (t == 0) {
            publish_f32(sHiA, sLoA, wv, lane, h0 + ((size_t)rowA << 10));
        } else {
            poll4(bufs + ((size_t)((t - 1) & 3) << 16) + ((size_t)rowA << 10), lane, dA);
            publish_u32(sHiA, sLoA, wv, lane, dA);
        }
        if (t > 0)   // B_t loads in flight across A's compute
            issue4(bufs + ((size_t)((t - 1) & 3) << 16) + ((size_t)rowB << 10), lane, dB);
        float e2pA = 0.f;
        if (tid < 256)
            e2pA = E2[(size_t)sX[(tid >> 5) * SEQ + t] * HIDDEN + j0 + (tid & 31)];
        __syncthreads();                                   // X1
        if (t >= 2) LREDUCE(sPLB, b0 + 8, t - 2);
        MFMA_MAIN(sHiA, sLoA, sPartA);
        __syncthreads();                                   // X2
        FINISH(sPartA, e2pA, b0);
        MFMA_LOGITS(sHiA, sPLA);

        // ================= B phase =================
        if (t == 0) {
            publish_f32(sHiB, sLoB, wv, lane, h0 + ((size_t)rowB << 10));
        } else {
            poll4(bufs + ((size_t)((t - 1) & 3) << 16) + ((size_t)rowB << 10), lane, dB);
            publish_u32(sHiB, sLoB, wv, lane, dB);
        }
        if (t < SEQ - 1)  // A_{t+1} loads in flight across B's compute
            issue4(bufs + ((size_t)(t & 3) << 16) + ((size_t)rowA << 10), lane, dA);
        float e2pB = 0.f;
        if (tid < 256)
            e2pB = E2[(size_t)sX[(8 + (tid >> 5)) * SEQ + t] * HIDDEN + j0 + (tid & 31)];
        __syncthreads();                                   // X3
        if (t >= 1) LREDUCE(sPLA, b0, t - 1);
        MFMA_MAIN(sHiB, sLoB, sPartB);
        __syncthreads();                                   // X4
        FINISH(sPartB, e2pB, b0 + 8);
        MFMA_LOGITS(sHiB, sPLB);
    }

    // ---- epilogue ----
    __syncthreads();
    LREDUCE(sPLB, b0 + 8, SEQ - 2);                        // B pos 510 (written last tick)
    {   // pos 511 for A and B from h_512 (slot (SEQ-1)&3 = 3)
        const unsigned int* sA = bufs + ((size_t)((SEQ - 1) & 3) << 16) + ((size_t)rowA << 10);
        const unsigned int* sB = bufs + ((size_t)((SEQ - 1) & 3) << 16) + ((size_t)rowB << 10);
        issue4(sA, lane, dA);
        poll4(sA, lane, dA);
        issue4(sB, lane, dB);
        poll4(sB, lane, dB);
        publish_u32(sHiA, sLoA, wv, lane, dA);
        publish_u32(sHiB, sLoB, wv, lane, dB);
    }
    __syncthreads();
    MFMA_LOGITS(sHiA, sPLA);
    MFMA_LOGITS(sHiB, sPLB);
    __syncthreads();
    LREDUCE(sPLA, b0, SEQ - 1);
    LREDUCE(sPLB, b0 + 8, SEQ - 1);
}

extern "C" void kernel_launch(void* const* d_in, const int* in_sizes, int n_in,
                              void* d_out, int out_size, void* d_ws, size_t ws_size,
                              hipStream_t stream) {
    (void)in_sizes; (void)n_in; (void)out_size; (void)ws_size;
    const int*   x     = (const int*)  d_in[0];
    const float* h0    = (const float*)d_in[1];
    const float* emb   = (const float*)d_in[2];
    const float* W_hx  = (const float*)d_in[3];
    const float* b_hx  = (const float*)d_in[4];
    const float* W_hh  = (const float*)d_in[5];
    const float* W_out = (const float*)d_in[6];
    const float* b_out = (const float*)d_in[7];

    float* logits = (float*)d_out;
    float* hf     = logits + (size_t)BATCH * SEQ * VOCAB;

    float* ws  = (float*)d_ws;
    float* E2  = ws + E2_OFF;
    unsigned short* WoT = (unsigned short*)(ws + WOT_OFF);
    unsigned int*   bufs = (unsigned int*)(ws + BUF_OFF);

    poison_kernel<<<256, 256, 0, stream>>>(bufs);
    e2_kernel<<<512, 256, 0, stream>>>(emb, W_hx, b_hx, E2);
    wot_kernel<<<128, 256, 0, stream>>>(W_out, WoT);

    hipFuncSetAttribute(reinterpret_cast<const void*>(rnn_kernel),
                        hipFuncAttributeMaxDynamicSharedMemorySize, 116736);
    rnn_kernel<<<128, NTHR, 116736, stream>>>(x, h0, W_hh, E2, WoT, b_out,
                                              bufs, logits, hf);
}

// Round 13
// 1696.063 us; speedup vs baseline: 1.1913x; 1.1913x over previous
//
#include <hip/hip_runtime.h>
#include <stdint.h>
#include <stddef.h>

#define VOCAB  128
#define HIDDEN 1024
#define BATCH  64
#define SEQ    512

#define NGROUP 4      // batch groups
#define BG     16     // batches per group
#define NWG    32     // workgroups per group (column slices)
#define CJ     32     // W_hh columns per WG
#define NVW    4      // vocab rows per WG (VOCAB/NWG)
#define NTHR   512

#define POISON 0x7F800000u   // (inf<<16): impossible for packed (bf16hi(tanh)<<16)|lo

// ws layout in float units
#define E2_OFF   0          // [128][1024] f32
#define WOT_OFF  131072     // [128][1024] bf16
#define BUF_OFF  196608     // [4][64][1024] u32 packed h

typedef __attribute__((ext_vector_type(8))) short short8_t;
typedef __attribute__((ext_vector_type(4))) float f32x4;

// ---------------- coherent (cross-XCD, MALL-level) access helpers ----------------
__device__ __forceinline__ uint4 cload4u(const void* p) {
    uint4 v;
    asm volatile("global_load_dwordx4 %0, %1, off sc0 sc1" : "=v"(v) : "v"(p));
    return v;
}
__device__ __forceinline__ void cstoreu(unsigned int* p, unsigned int x) {
    asm volatile("global_store_dword %0, %1, off sc0 sc1" :: "v"(p), "v"(x) : "memory");
}
// rule-18 discipline: asm-load results are consumed ONLY within the same
// straight-line block as issue -> WAITVM0 -> SCHED_FENCE -> use. Never carried
// across barriers or loop back-edges (r12 lesson: compiler-inserted copies of
// asm-output regs don't wait on vmcnt).
#define WAITVM0() asm volatile("s_waitcnt vmcnt(0)" ::: "memory")
#define SCHED_FENCE() __builtin_amdgcn_sched_barrier(0)

// ---------------- bf16 helpers ----------------
__device__ __forceinline__ unsigned short bf16_rne(float f) {
    unsigned int u = __float_as_uint(f);
    u += 0x7FFF + ((u >> 16) & 1);
    return (unsigned short)(u >> 16);
}
__device__ __forceinline__ float bf16_f32(unsigned short h) {
    return __uint_as_float(((unsigned int)h) << 16);
}
__device__ __forceinline__ bool ok8(const uint4 a, const uint4 b) {
    return a.x != POISON && a.y != POISON && a.z != POISON && a.w != POISON
        && b.x != POISON && b.y != POISON && b.z != POISON && b.w != POISON;
}
__device__ __forceinline__ void unpack8(const uint4 a, const uint4 b,
                                        short8_t* h8, short8_t* l8) {
    (*h8)[0]=(short)(a.x>>16); (*l8)[0]=(short)(a.x&0xFFFF);
    (*h8)[1]=(short)(a.y>>16); (*l8)[1]=(short)(a.y&0xFFFF);
    (*h8)[2]=(short)(a.z>>16); (*l8)[2]=(short)(a.z&0xFFFF);
    (*h8)[3]=(short)(a.w>>16); (*l8)[3]=(short)(a.w&0xFFFF);
    (*h8)[4]=(short)(b.x>>16); (*l8)[4]=(short)(b.x&0xFFFF);
    (*h8)[5]=(short)(b.y>>16); (*l8)[5]=(short)(b.y&0xFFFF);
    (*h8)[6]=(short)(b.z>>16); (*l8)[6]=(short)(b.z&0xFFFF);
    (*h8)[7]=(short)(b.w>>16); (*l8)[7]=(short)(b.w&0xFFFF);
}

// ---------------- E2 = emb @ W_hx + b_hx  ([128][1024] f32) ----------------
__global__ void e2_kernel(const float* __restrict__ emb, const float* __restrict__ W_hx,
                          const float* __restrict__ b_hx, float* __restrict__ E2) {
    int v = blockIdx.x >> 2;
    int j = (blockIdx.x & 3) * 256 + threadIdx.x;
    const float* er = emb + (size_t)v * HIDDEN;
    float acc = 0.f;
#pragma unroll 8
    for (int k = 0; k < HIDDEN; ++k)
        acc += er[k] * W_hx[(size_t)k * HIDDEN + j];
    E2[(size_t)v * HIDDEN + j] = acc + b_hx[j];
}

// ---------------- WoT[v][k] = bf16(W_out[k][v]) ----------------
__global__ void wot_kernel(const float* __restrict__ W_out, unsigned short* __restrict__ WoT) {
    int v  = blockIdx.x;
    int k4 = threadIdx.x;
    ushort4 r;
    r.x = bf16_rne(W_out[(size_t)(k4*4+0)*VOCAB + v]);
    r.y = bf16_rne(W_out[(size_t)(k4*4+1)*VOCAB + v]);
    r.z = bf16_rne(W_out[(size_t)(k4*4+2)*VOCAB + v]);
    r.w = bf16_rne(W_out[(size_t)(k4*4+3)*VOCAB + v]);
    ((ushort4*)(WoT + (size_t)v * HIDDEN))[k4] = r;
}

// ---------------- poison init (graph-replay deterministic) ----------------
__global__ void poison_kernel(unsigned int* __restrict__ bufs) {
    int i = blockIdx.x * 256 + threadIdx.x;
    ((uint4*)bufs)[i] = make_uint4(POISON, POISON, POISON, POISON);
}

// ---------------- persistent recurrence kernel ----------------
// grid = 128 blocks (4 groups x 32 col-slices), 512 threads (8 waves), 114KB LDS.
// r8 data path; 2 barriers/step: logits MFMA fused into the main c-loop (CSE'd
// ds_reads) writing a dedicated sPLog region; finish + logits-reduce both after (b).
extern "C" __global__ void __launch_bounds__(NTHR, 2)
rnn_kernel(const int* __restrict__ x, const float* __restrict__ h0,
           const float* __restrict__ W_hh,
           const float* __restrict__ E2, const unsigned short* __restrict__ WoT,
           const float* __restrict__ b_out,
           unsigned int* __restrict__ bufs,
           float* __restrict__ logits, float* __restrict__ hf) {
    extern __shared__ char lds_raw[];
    short* sHi   = (short*)lds_raw;                 // [16][1024] bf16 hi, swz: 32KB
    short* sLo   = (short*)(lds_raw + 32768);       // 32KB
    float* sPart = (float*)(lds_raw + 65536);       // [8][512] f32: 16KB
    float* sPLog = (float*)(lds_raw + 81920);       // [8][64] f32: 2KB
    int*   sX    = (int*)(lds_raw + 83968);         // [16][512] int: 32KB

    const int wg = blockIdx.x;
    const int g  = wg / NWG;
    const int w  = wg % NWG;
    const int b0 = g * BG;
    const int j0 = w * CJ;
    const int tid  = threadIdx.x;
    const int lane = tid & 63;
    const int wv   = tid >> 6;

    // ---- prologue: x slice -> LDS ----
    {
        const int4* xs4 = (const int4*)(x + (size_t)b0 * SEQ);
#pragma unroll
        for (int i = 0; i < 4; ++i)
            ((int4*)sX)[tid + 512 * i] = xs4[tid + 512 * i];
    }

    // ---- prologue: W_hh column slice -> bf16 hi/lo fragments in VGPRs ----
    // wave wv owns k in [wv*128, wv*128+128); B-frag: lane l holds B[k=(l>>4)*8+e][col=l&15]
    short8_t whi[2][4], wlo[2][4];
    {
        const int colb = lane & 15, kgrp = lane >> 4;
#pragma unroll
        for (int ct = 0; ct < 2; ++ct) {
            int col = j0 + ct * 16 + colb;
#pragma unroll
            for (int c = 0; c < 4; ++c) {
                int kb = wv * 128 + c * 32 + kgrp * 8;
#pragma unroll
                for (int e = 0; e < 8; ++e) {
                    float wval = W_hh[(size_t)(kb + e) * HIDDEN + col];
                    unsigned short hi = bf16_rne(wval);
                    whi[ct][c][e] = (short)hi;
                    wlo[ct][c][e] = (short)bf16_rne(wval - bf16_f32(hi));
                }
            }
        }
    }

    // ---- prologue: W_out slice (NVW=4 vocab rows) -> bf16 B-frags (cols 4..15 zero) ----
    short8_t wvo[4];
    {
        const int colv = lane & 15, kgrp = lane >> 4;
#pragma unroll
        for (int c = 0; c < 4; ++c) {
            int kb = wv * 128 + c * 32 + kgrp * 8;
#pragma unroll
            for (int e = 0; e < 8; ++e)
                wvo[c][e] = (colv < NVW)
                    ? (short)WoT[(size_t)(w * NVW + colv) * HIDDEN + kb + e] : (short)0;
        }
    }
    const float boV = (tid < 64) ? b_out[w * NVW + (tid & 3)] : 0.f;
    __syncthreads();

    const int srow = tid >> 5;                  // staging row [0,16)
    const int sslt = tid & 31;                  // staging chunk slot
    const int rb = tid >> 5, jb = tid & 31;     // finish mapping: batch, col
    const int ar = lane & 15, acg = lane >> 4;  // A-frag row / k-group

    for (int t = 0; t < SEQ; ++t) {
        float e2p = E2[(size_t)sX[rb * SEQ + t] * HIDDEN + j0 + jb];

        // ---- stage h_t into LDS (bf16 hi/lo, 16B chunk c stored at c^(row&7)) ----
        if (t == 0) {
#pragma unroll
            for (int i = 0; i < 4; ++i) {
                int c = i * 32 + sslt;
                const float* p = h0 + (size_t)(b0 + srow) * HIDDEN + c * 8;
                short8_t h8, l8;
#pragma unroll
                for (int e = 0; e < 8; ++e) {
                    float vv = p[e];
                    unsigned short hi = bf16_rne(vv);
                    h8[e] = (short)hi;
                    l8[e] = (short)bf16_rne(vv - bf16_f32(hi));
                }
                int cs = (c ^ (srow & 7)) << 3;
                *(short8_t*)(sHi + srow * 1024 + cs) = h8;
                *(short8_t*)(sLo + srow * 1024 + cs) = l8;
            }
        } else {
            // ---- poll-on-data: h_t lives in buf[(t-1)&3], issue+wait+check in one block ----
            const unsigned int* src = bufs + ((size_t)((t - 1) & 3) << 16)
                                           + ((size_t)(b0 + srow) << 10);
            uint4 d[8];
            unsigned pend = 0xF;
            int guard = 0;
            do {
#pragma unroll
                for (int i = 0; i < 4; ++i)
                    if (pend & (1u << i)) {
                        int c = i * 32 + sslt;
                        d[2*i]   = cload4u(src + c * 8);
                        d[2*i+1] = cload4u(src + c * 8 + 4);
                    }
                WAITVM0();
                SCHED_FENCE();   // rule 18: checks AFTER the hardware wait
                if ((pend & 1u) && ok8(d[0], d[1])) pend &= ~1u;
                if ((pend & 2u) && ok8(d[2], d[3])) pend &= ~2u;
                if ((pend & 4u) && ok8(d[4], d[5])) pend &= ~4u;
                if ((pend & 8u) && ok8(d[6], d[7])) pend &= ~8u;
                if (!pend) break;
                __builtin_amdgcn_s_sleep(1);
            } while (++guard < (1 << 20));
            SCHED_FENCE();
#pragma unroll
            for (int i = 0; i < 4; ++i) {
                int c = i * 32 + sslt;
                int cs = (c ^ (srow & 7)) << 3;
                short8_t h8, l8;
                unpack8(d[2*i], d[2*i+1], &h8, &l8);
                *(short8_t*)(sHi + srow * 1024 + cs) = h8;
                *(short8_t*)(sLo + srow * 1024 + cs) = l8;
            }
        }
        __syncthreads();   // (a)

        // ---- MFMA phase: main (24 MFMA) + fused logits (4 MFMA, CSE'd ahi reads) ----
        f32x4 acc0 = {0.f, 0.f, 0.f, 0.f};
        f32x4 acc1 = {0.f, 0.f, 0.f, 0.f};
        f32x4 accL = {0.f, 0.f, 0.f, 0.f};
#pragma unroll
        for (int c = 0; c < 4; ++c) {
            int c8 = wv * 16 + c * 4 + acg;          // logical 16B chunk of row ar
            int off = ar * 1024 + ((c8 ^ (ar & 7)) << 3);
            short8_t ahi = *(const short8_t*)(sHi + off);
            short8_t alo = *(const short8_t*)(sLo + off);
            acc0 = __builtin_amdgcn_mfma_f32_16x16x32_bf16(ahi, whi[0][c], acc0, 0, 0, 0);
            acc1 = __builtin_amdgcn_mfma_f32_16x16x32_bf16(ahi, whi[1][c], acc1, 0, 0, 0);
            acc0 = __builtin_amdgcn_mfma_f32_16x16x32_bf16(alo, whi[0][c], acc0, 0, 0, 0);
            acc1 = __builtin_amdgcn_mfma_f32_16x16x32_bf16(alo, whi[1][c], acc1, 0, 0, 0);
            acc0 = __builtin_amdgcn_mfma_f32_16x16x32_bf16(ahi, wlo[0][c], acc0, 0, 0, 0);
            acc1 = __builtin_amdgcn_mfma_f32_16x16x32_bf16(ahi, wlo[1][c], acc1, 0, 0, 0);
            if (t > 0)
                accL = __builtin_amdgcn_mfma_f32_16x16x32_bf16(ahi, wvo[c], accL, 0, 0, 0);
        }
        // C layout: col=lane&15, row=(lane>>4)*4+q  -> sPart[wv][row][col(+16*ct)]
#pragma unroll
        for (int q = 0; q < 4; ++q) {
            sPart[wv * 512 + (acg * 4 + q) * 32 + ar]      = acc0[q];
            sPart[wv * 512 + (acg * 4 + q) * 32 + 16 + ar] = acc1[q];
        }
        if (t > 0 && ar < NVW) {
#pragma unroll
            for (int q = 0; q < 4; ++q)
                sPLog[wv * 64 + (acg * 4 + q) * 4 + ar] = accL[q];
        }
        __syncthreads();   // (b)

        // ---- finish: reduce 8 partials + E2 + tanh; fire-and-forget packed store ----
        {
            float s = 0.f;
#pragma unroll
            for (int z = 0; z < 8; ++z) s += sPart[z * 512 + tid];
            float hn = tanhf(s + e2p);
            unsigned short hi = bf16_rne(hn);
            unsigned short lo = bf16_rne(hn - bf16_f32(hi));
            unsigned int pk = ((unsigned int)hi << 16) | (unsigned int)lo;
            size_t idx = ((size_t)(b0 + rb) << 10) + j0 + jb;
            cstoreu(bufs + ((size_t)(t & 3) << 16) + idx, pk);             // data
            cstoreu(bufs + ((size_t)((t + 2) & 3) << 16) + idx, POISON);   // re-arm
            if (t == SEQ - 1)
                hf[(size_t)(b0 + rb) * HIDDEN + j0 + jb] = hn;
        }

        // ---- logits reduce for position t-1 (no further barrier; sPLog/sPart
        //      are next written only after (a)@t+1, which all readers gate) ----
        if (t > 0 && tid < 64) {
            int b = tid >> 2, v = tid & 3;
            float s = 0.f;
#pragma unroll
            for (int z = 0; z < 8; ++z) s += sPLog[z * 64 + b * 4 + v];
            logits[((size_t)(b0 + b) * SEQ + (t - 1)) * VOCAB + w * NVW + v] = s + boV;
        }
    }

    // ---- epilogue: logits for position SEQ-1 from h_SEQ (buf[3], hi only) ----
    {
        const unsigned int* src = bufs + ((size_t)((SEQ - 1) & 3) << 16)
                                       + ((size_t)(b0 + srow) << 10);
        uint4 d[8];
        unsigned pend = 0xF;
        int guard = 0;
        do {
#pragma unroll
            for (int i = 0; i < 4; ++i)
                if (pend & (1u << i)) {
                    int c = i * 32 + sslt;
                    d[2*i]   = cload4u(src + c * 8);
                    d[2*i+1] = cload4u(src + c * 8 + 4);
                }
            WAITVM0();
            SCHED_FENCE();
            if ((pend & 1u) && ok8(d[0], d[1])) pend &= ~1u;
            if ((pend & 2u) && ok8(d[2], d[3])) pend &= ~2u;
            if ((pend & 4u) && ok8(d[4], d[5])) pend &= ~4u;
            if ((pend & 8u) && ok8(d[6], d[7])) pend &= ~8u;
            if (!pend) break;
            __builtin_amdgcn_s_sleep(1);
        } while (++guard < (1 << 20));
        SCHED_FENCE();
#pragma unroll
        for (int i = 0; i < 4; ++i) {
            int c = i * 32 + sslt;
            int cs = (c ^ (srow & 7)) << 3;
            short8_t h8, l8;
            unpack8(d[2*i], d[2*i+1], &h8, &l8);
            *(short8_t*)(sHi + srow * 1024 + cs) = h8;
        }
    }
    __syncthreads();
    {
        f32x4 accL = {0.f, 0.f, 0.f, 0.f};
#pragma unroll
        for (int c = 0; c < 4; ++c) {
            int c8 = wv * 16 + c * 4 + acg;
            int off = ar * 1024 + ((c8 ^ (ar & 7)) << 3);
            short8_t ahi = *(const short8_t*)(sHi + off);
            accL = __builtin_amdgcn_mfma_f32_16x16x32_bf16(ahi, wvo[c], accL, 0, 0, 0);
        }
        if (ar < NVW) {
#pragma unroll
            for (int q = 0; q < 4; ++q)
                sPLog[wv * 64 + (acg * 4 + q) * 4 + ar] = accL[q];
        }
        __syncthreads();
        if (tid < 64) {
            int b = tid >> 2, v = tid & 3;
            float s = 0.f;
#pragma unroll
            for (int z = 0; z < 8; ++z) s += sPLog[z * 64 + b * 4 + v];
            logits[((size_t)(b0 + b) * SEQ + (SEQ - 1)) * VOCAB + w * NVW + v] = s + boV;
        }
    }
}

extern "C" void kernel_launch(void* const* d_in, const int* in_sizes, int n_in,
                              void* d_out, int out_size, void* d_ws, size_t ws_size,
                              hipStream_t stream) {
    (void)in_sizes; (void)n_in; (void)out_size; (void)ws_size;
    const int*   x     = (const int*)  d_in[0];
    const float* h0    = (const float*)d_in[1];
    const float* emb   = (const float*)d_in[2];
    const float* W_hx  = (const float*)d_in[3];
    const float* b_hx  = (const float*)d_in[4];
    const float* W_hh  = (const float*)d_in[5];
    const float* W_out = (const float*)d_in[6];
    const float* b_out = (const float*)d_in[7];

    float* logits = (float*)d_out;
    float* hf     = logits + (size_t)BATCH * SEQ * VOCAB;

    float* ws  = (float*)d_ws;
    float* E2  = ws + E2_OFF;
    unsigned short* WoT = (unsigned short*)(ws + WOT_OFF);
    unsigned int*   bufs = (unsigned int*)(ws + BUF_OFF);

    poison_kernel<<<256, 256, 0, stream>>>(bufs);
    e2_kernel<<<512, 256, 0, stream>>>(emb, W_hx, b_hx, E2);
    wot_kernel<<<128, 256, 0, stream>>>(W_out, WoT);

    hipFuncSetAttribute(reinterpret_cast<const void*>(rnn_kernel),
                        hipFuncAttributeMaxDynamicSharedMemorySize, 116736);
    rnn_kernel<<<NGROUP * NWG, NTHR, 116736, stream>>>(x, h0, W_hh, E2, WoT, b_out,
                                                       bufs, logits, hf);
}